// Round 4
// baseline (352.763 us; speedup 1.0000x reference)
//
#include <hip/hip_runtime.h>
#include <hip/hip_bf16.h>

#define CIN   128
#define EMBD  64
#define KC    512
#define SPAT  32768
#define NVOX  131072
#define QSZ   (NVOX * EMBD)      // 8388608
#define DIFF_OFF QSZ
#define IDX_OFF  (QSZ + 1)

// ---------------------------------------------------------------------------
// Prep: embedT[k][o] = embed[o][k]  (row-major codebook rows for fast dot),
// norms[k] = sum_o embed[o][k]^2
// ---------------------------------------------------------------------------
__global__ __launch_bounds__(64) void vq_prep(const float* __restrict__ embed,
                                              float* __restrict__ embedT,
                                              float* __restrict__ norms) {
  int k = blockIdx.x;   // 512
  int o = threadIdx.x;  // 64
  float e = embed[o * KC + k];
  embedT[k * EMBD + o] = e;
  float s = e * e;
  #pragma unroll
  for (int off = 32; off > 0; off >>= 1) s += __shfl_down(s, off);
  if (o == 0) norms[k] = s;
}

// ---------------------------------------------------------------------------
// Main: per-thread voxel. conv (128->64) -> argmin over 512 codes -> outputs.
// ---------------------------------------------------------------------------
__global__ __launch_bounds__(256, 2) void vq_main(
    const float* __restrict__ x, const float* __restrict__ conv_w,
    const float* __restrict__ conv_b, const float* __restrict__ embedT,
    const float* __restrict__ norms, float* __restrict__ out,
    float* __restrict__ partials) {
  // conv_w staged as [c][o], row stride 68 floats (keeps staging writes off a
  // single bank; reads are wave-uniform broadcasts so layout only matters for
  // the one-time staging).
  __shared__ float wlds[CIN * 68];
  for (int f = threadIdx.x; f < CIN * EMBD; f += 256) {
    int o = f >> 7;          // conv_w is (EMB=64, C=128): conv_w[o*128+c]
    int c = f & (CIN - 1);
    wlds[c * 68 + o] = conv_w[f];
  }
  __syncthreads();

  const int n = blockIdx.x * 256 + threadIdx.x;  // voxel id
  const int b = n >> 15;
  const int v = n & (SPAT - 1);
  const float* xp = x + ((size_t)b * CIN) * SPAT + v;

  // z = W x + b  (64 accumulators in registers)
  float z[EMBD];
  #pragma unroll
  for (int o = 0; o < EMBD; ++o) z[o] = conv_b[o];

  for (int c = 0; c < CIN; ++c) {
    float xv = xp[(size_t)c * SPAT];       // coalesced across lanes
    const float* wr = &wlds[c * 68];
    #pragma unroll
    for (int o = 0; o < EMBD; ++o) z[o] = fmaf(xv, wr[o], z[o]);
  }

  // argmin_k ( ||e_k||^2 - 2 z.e_k )   (||z||^2 constant per voxel)
  float best = 3.4e38f;
  int bi = 0;
  for (int k = 0; k < KC; ++k) {
    const float* ek = embedT + k * EMBD;   // wave-uniform address
    float d0 = 0.f, d1 = 0.f, d2 = 0.f, d3 = 0.f;
    #pragma unroll
    for (int o = 0; o < EMBD; o += 4) {
      float4 e4 = *(const float4*)(ek + o);
      d0 = fmaf(z[o + 0], e4.x, d0);
      d1 = fmaf(z[o + 1], e4.y, d1);
      d2 = fmaf(z[o + 2], e4.z, d2);
      d3 = fmaf(z[o + 3], e4.w, d3);
    }
    float dot = (d0 + d1) + (d2 + d3);
    float s = fmaf(-2.f, dot, norms[k]);
    if (s < best) { best = s; bi = k; }    // strict < keeps first (= jnp.argmin)
  }

  // Gather chosen code, write quantize (B,EMB,D,H,W), accumulate local diff.
  const float* eb = embedT + bi * EMBD;    // per-lane gather, L2-resident
  float* qout = out + ((size_t)b * EMBD) * SPAT + v;
  float diff = 0.f;
  #pragma unroll
  for (int o = 0; o < EMBD; ++o) {
    float e = eb[o];
    float r = e - z[o];
    diff = fmaf(r, r, diff);
    qout[(size_t)o * SPAT] = e;            // coalesced across lanes per o
  }
  out[IDX_OFF + n] = (float)bi;

  // block-reduce diff -> partials[block]
  #pragma unroll
  for (int off = 32; off > 0; off >>= 1) diff += __shfl_down(diff, off);
  __syncthreads();                          // done with wlds; reuse
  if ((threadIdx.x & 63) == 0) wlds[threadIdx.x >> 6] = diff;
  __syncthreads();
  if (threadIdx.x == 0)
    partials[blockIdx.x] = wlds[0] + wlds[1] + wlds[2] + wlds[3];
}

__global__ __launch_bounds__(512) void vq_final(const float* __restrict__ partials,
                                                float* __restrict__ out) {
  __shared__ float tmp[8];
  float s = partials[threadIdx.x];   // 512 partials, 512 threads
  #pragma unroll
  for (int off = 32; off > 0; off >>= 1) s += __shfl_down(s, off);
  if ((threadIdx.x & 63) == 0) tmp[threadIdx.x >> 6] = s;
  __syncthreads();
  if (threadIdx.x == 0) {
    float t = 0.f;
    #pragma unroll
    for (int i = 0; i < 8; ++i) t += tmp[i];
    out[DIFF_OFF] = t * (1.0f / (float)QSZ);
  }
}

extern "C" void kernel_launch(void* const* d_in, const int* in_sizes, int n_in,
                              void* d_out, int out_size, void* d_ws, size_t ws_size,
                              hipStream_t stream) {
  const float* x      = (const float*)d_in[0];
  const float* conv_w = (const float*)d_in[1];
  const float* conv_b = (const float*)d_in[2];
  const float* embed  = (const float*)d_in[3];
  float* out = (float*)d_out;
  float* ws  = (float*)d_ws;

  float* embedT   = ws;            // 32768 floats (128 KB)
  float* norms    = ws + 32768;    // 512 floats
  float* partials = ws + 33280;    // 512 floats

  vq_prep<<<KC, EMBD, 0, stream>>>(embed, embedT, norms);
  vq_main<<<NVOX / 256, 256, 0, stream>>>(x, conv_w, conv_b, embedT, norms,
                                          out, partials);
  vq_final<<<1, 512, 0, stream>>>(partials, out);
}